// Round 3
// baseline (1258.407 us; speedup 1.0000x reference)
//
#include <hip/hip_runtime.h>
#include <hip/hip_bf16.h>
#include <math.h>

#define DI __device__ __forceinline__

typedef unsigned short u16;
typedef unsigned int   u32;
typedef unsigned long long u64;
typedef __attribute__((ext_vector_type(8))) short short8;   // 8 bf16 (4 VGPRs) MFMA A/B frag
typedef __attribute__((ext_vector_type(4))) float f32x4;    // MFMA C/D frag

constexpr int CB = 512;    // channels
constexpr int LL = 4096;   // length
constexpr int NG = 32;     // groups

DI float bf2f(u16 u) { u32 v = ((u32)u) << 16; float f; __builtin_memcpy(&f, &v, 4); return f; }
DI u16 f2bf(float f) {
  u32 u; __builtin_memcpy(&u, &f, 4);
  u += 0x7fffu + ((u >> 16) & 1u);   // RNE
  return (u16)(u >> 16);
}

DI void gload16(const void* g, void* l) {
  __builtin_amdgcn_global_load_lds((const __attribute__((address_space(1))) u32*)g,
                                   (__attribute__((address_space(3))) u32*)l, 16, 0, 0);
}

// raw barrier + counted waitcnt helpers (rule #18: sched_barrier after asm waitcnt)
DI void bar_lgkm() {
  asm volatile("s_waitcnt lgkmcnt(0)" ::: "memory");
  __builtin_amdgcn_sched_barrier(0);
  __builtin_amdgcn_s_barrier();
}
DI void bar_vm8_lgkm() {
  asm volatile("s_waitcnt vmcnt(8) lgkmcnt(0)" ::: "memory");
  __builtin_amdgcn_sched_barrier(0);
  __builtin_amdgcn_s_barrier();
}
DI void bar_vm0_lgkm() {
  asm volatile("s_waitcnt vmcnt(0) lgkmcnt(0)" ::: "memory");
  __builtin_amdgcn_sched_barrier(0);
  __builtin_amdgcn_s_barrier();
}

// ---------------------------------------------------------------------------
// K0: weights -> bf16 (wqkv fused [1536][512], wo [512][512]); fused bias.
// ---------------------------------------------------------------------------
__global__ __launch_bounds__(256) void conv_w(
    const float* __restrict__ wq, const float* __restrict__ wk,
    const float* __restrict__ wv, const float* __restrict__ wo,
    const float* __restrict__ bq, const float* __restrict__ bk,
    const float* __restrict__ bv,
    u16* __restrict__ wqkv, u16* __restrict__ wob, float* __restrict__ bqkv) {
  if (blockIdx.x < 1024) {
    int i = blockIdx.x * 256 + threadIdx.x;
    wqkv[i]          = f2bf(wq[i]);
    wqkv[262144 + i] = f2bf(wk[i]);
    wqkv[524288 + i] = f2bf(wv[i]);
    wob[i]           = f2bf(wo[i]);
  } else {
    for (int j = 0; j < 6; ++j) {
      int idx = j * 256 + threadIdx.x;
      float b = (idx < 512) ? bq[idx] : (idx < 1024) ? bk[idx - 512] : bv[idx - 1024];
      bqkv[idx] = b;
    }
  }
}

// ---------------------------------------------------------------------------
// K1: GroupNorm stats. One block per (b,g).
// ---------------------------------------------------------------------------
__global__ __launch_bounds__(256) void gn_stats(const float* __restrict__ x,
                                                float* __restrict__ stats) {
  const float4* base = (const float4*)(x + (long)blockIdx.x * (16 * LL));
  float s = 0.f, ss = 0.f;
  for (int i = threadIdx.x; i < 16 * LL / 4; i += 256) {
    float4 v = base[i];
    s  += v.x + v.y + v.z + v.w;
    ss += v.x * v.x + v.y * v.y + v.z * v.z + v.w * v.w;
  }
#pragma unroll
  for (int o = 32; o; o >>= 1) { s += __shfl_xor(s, o); ss += __shfl_xor(ss, o); }
  __shared__ float red[8];
  int wv = threadIdx.x >> 6, ln = threadIdx.x & 63;
  if (ln == 0) { red[wv * 2] = s; red[wv * 2 + 1] = ss; }
  __syncthreads();
  if (threadIdx.x == 0) {
    float S = red[0] + red[2] + red[4] + red[6];
    float SS = red[1] + red[3] + red[5] + red[7];
    float mu = S * (1.f / 65536.f);
    float var = SS * (1.f / 65536.f) - mu * mu;
    stats[blockIdx.x * 2]     = mu;
    stats[blockIdx.x * 2 + 1] = rsqrtf(var + 1e-6f);
  }
}

// ---------------------------------------------------------------------------
// K2: GroupNorm apply + transpose: hT[b][l][c] = bf16(gn(x[b][c][l]))
// ---------------------------------------------------------------------------
__global__ __launch_bounds__(256) void gn_apply(
    const float* __restrict__ x, const float* __restrict__ gw,
    const float* __restrict__ gb, const float* __restrict__ stats,
    u16* __restrict__ hT) {
  __shared__ u16 t[64][66];
  const int b = blockIdx.z, c0 = blockIdx.y * 64, l0 = blockIdx.x * 64;
  const int ln = threadIdx.x & 63, sub = threadIdx.x >> 6;
  for (int cr = sub; cr < 64; cr += 4) {
    int c = c0 + cr;
    float v  = x[(long)b * CB * LL + (long)c * LL + l0 + ln];
    float mu = stats[(b * NG + (c >> 4)) * 2];
    float rs = stats[(b * NG + (c >> 4)) * 2 + 1];
    t[cr][ln] = f2bf((v - mu) * rs * gw[c] + gb[c]);
  }
  __syncthreads();
  for (int lr = sub; lr < 64; lr += 4)
    hT[(long)b * LL * CB + (long)(l0 + lr) * CB + c0 + ln] = t[ln][lr];
}

// ---------------------------------------------------------------------------
// GEMM skeleton (m97 structure): D[M][N] = A[M][K] * Bt[N][K]^T
// EPI: 0=QKV (q/k -> [l][c], v -> [c][l]; +bias)   3=out (fp32 +bias +res)
// ---------------------------------------------------------------------------
template <int BM, int BN, int EPI>
__global__ __launch_bounds__(256) void gemm_bt(
    const u16* __restrict__ A, int lda, long asb,
    const u16* __restrict__ Bt, int ldb, long bsb,
    int K, const float* __restrict__ bias,
    u16* __restrict__ o0, u16* __restrict__ o1, u16* __restrict__ o2,
    float* __restrict__ of, const float* __restrict__ xres, long osb, int ldo) {
  constexpr int FM = BM / 32, FN = BN / 32;
  __shared__ u16 smem[(BM + BN) * 64];
  u16* lA = smem;
  u16* lB = smem + BM * 64;

  const int bx = blockIdx.x, by = blockIdx.y;
  const int tid = threadIdx.x;
  const int lane = tid & 63;
  const int wv = tid >> 6;
  const int wr = wv >> 1, wc = wv & 1;
  const int fr = lane & 15, fq = lane >> 4;
  const int bz = blockIdx.z;

  const u16* Ab = A + (long)bz * asb + (long)(by * BM) * lda;
  const u16* Bb = Bt + (long)bz * bsb + (long)(bx * BN) * ldb;

  f32x4 acc[FM][FN];
#pragma unroll
  for (int m = 0; m < FM; ++m)
#pragma unroll
    for (int n = 0; n < FN; ++n) acc[m][n] = (f32x4)(0.f);

  for (int k0 = 0; k0 < K; k0 += 64) {
#pragma unroll
    for (int p = 0; p < BM / 32; ++p) {
      int t = p * 256 + tid;
      int row = t >> 3;
      int cbl = ((t & 7) << 4) ^ ((row & 7) << 4);
      gload16(Ab + (long)row * lda + k0 + (cbl >> 1), &lA[t * 8]);
    }
#pragma unroll
    for (int p = 0; p < BN / 32; ++p) {
      int t = p * 256 + tid;
      int row = t >> 3;
      int cbl = ((t & 7) << 4) ^ ((row & 7) << 4);
      gload16(Bb + (long)row * ldb + k0 + (cbl >> 1), &lB[t * 8]);
    }
    __syncthreads();
#pragma unroll
    for (int ks = 0; ks < 2; ++ks) {
      short8 af[FM], bfr[FN];
#pragma unroll
      for (int m = 0; m < FM; ++m) {
        int row = wr * (BM / 2) + m * 16 + fr;
        int cb = (ks * 64 + fq * 16) ^ ((row & 7) << 4);
        af[m] = *(const short8*)((const char*)lA + row * 128 + cb);
      }
#pragma unroll
      for (int n = 0; n < FN; ++n) {
        int row = wc * (BN / 2) + n * 16 + fr;
        int cb = (ks * 64 + fq * 16) ^ ((row & 7) << 4);
        bfr[n] = *(const short8*)((const char*)lB + row * 128 + cb);
      }
#pragma unroll
      for (int m = 0; m < FM; ++m)
#pragma unroll
        for (int n = 0; n < FN; ++n)
          acc[m][n] = __builtin_amdgcn_mfma_f32_16x16x32_bf16(af[m], bfr[n], acc[m][n], 0, 0, 0);
    }
    __syncthreads();
  }

  const int ml0 = wr * (BM / 2);
  const int nl0 = wc * (BN / 2);

  if constexpr (EPI == 3) {
    const int mg0 = by * BM + ml0;
    const int ng0 = bx * BN + nl0;
#pragma unroll
    for (int m = 0; m < FM; ++m)
#pragma unroll
      for (int n = 0; n < FN; ++n) {
        const int ng = ng0 + n * 16 + fr;
#pragma unroll
        for (int r = 0; r < 4; ++r) {
          const int mg = mg0 + m * 16 + fq * 4 + r;
          const long off = (long)bz * osb + (long)mg * ldo + ng;
          of[off] = acc[m][n][r] + bias[mg] + xres[off];
        }
      }
  } else {
    const int mat = (by * BM) >> 9;
    if (mat < 2) {
      // q/k: transposed tile in LDS: row = l (nl), col = c (ml), width BM
#pragma unroll
      for (int m = 0; m < FM; ++m)
#pragma unroll
        for (int n = 0; n < FN; ++n) {
          const int nl = nl0 + n * 16 + fr;
#pragma unroll
          for (int r = 0; r < 4; ++r) {
            const int ml = ml0 + m * 16 + fq * 4 + r;
            smem[nl * BM + (ml ^ ((nl & 7) << 3))] =
                f2bf(acc[m][n][r] + bias[by * BM + ml]);
          }
        }
      __syncthreads();
      u16* dst0 = (mat == 0 ? o0 : o1) + (long)bz * ((long)LL * CB) +
                  (long)(bx * BN) * CB + ((by * BM) & 511);
      for (int i = tid * 8; i < BM * BN; i += 2048) {
        const int rr = i / BM, cc = i % BM;
        short8 val = *(const short8*)&smem[rr * BM + (cc ^ ((rr & 7) << 3))];
        *(short8*)(dst0 + (long)rr * CB + cc) = val;
      }
    } else {
      // v: natural tile: row = c (ml), col = l (nl), width BN
#pragma unroll
      for (int m = 0; m < FM; ++m)
#pragma unroll
        for (int n = 0; n < FN; ++n) {
          const int nl = nl0 + n * 16 + fr;
#pragma unroll
          for (int r = 0; r < 4; ++r) {
            const int ml = ml0 + m * 16 + fq * 4 + r;
            smem[ml * BN + (nl ^ ((ml & 7) << 3))] =
                f2bf(acc[m][n][r] + bias[by * BM + ml]);
          }
        }
      __syncthreads();
      u16* dst0 = o2 + (long)bz * ((long)CB * LL) +
                  (long)((by * BM) & 511) * LL + bx * BN;
      for (int i = tid * 8; i < BM * BN; i += 2048) {
        const int rr = i / BN, cc = i % BN;
        short8 val = *(const short8*)&smem[rr * BN + (cc ^ ((rr & 7) << 3))];
        *(short8*)(dst0 + (long)rr * LL + cc) = val;
      }
    }
  }
}

// ---------------------------------------------------------------------------
// K3: fused flash attention.  Per block: 128 Q-rows of one batch z.
//   qT,kT: [z][l][c] bf16; vN: [z][c][l] bf16; out aT: [z][l][c] bf16.
//   8 waves: S-phase wave = 16 rows x 64 keys (Q frags in regs);
//   PV wave = 64-wide d-slice, all 128 rows (acc 32 f32x4).
//   K/V/P in LDS, XOR-swizzled; counted-vmcnt pipeline (T3/T4);
//   online softmax in log2 units with defer-max (T13, THR=11.5).
// ---------------------------------------------------------------------------
constexpr int QB = 128, KB = 64;

__global__ __launch_bounds__(512, 2) void attn_flash(
    const u16* __restrict__ qT, const u16* __restrict__ kT,
    const u16* __restrict__ vN, u16* __restrict__ aT) {
  __shared__ u16 smem[64 * 512 + 512 * 64 + 128 * 64];   // K | V | P = 147456 B
  u16* lK = smem;                 // [key][512] elems, swz: c8 ^= (key&7)
  u16* lV = smem + 64 * 512;      // [d][64] elems,    swz: k8 ^= (d&7)
  u16* lP = smem + 64 * 512 + 512 * 64;  // [row][64],  swz: k8 ^= (row&7)
  __shared__ float mst[QB], lst[QB], mxn[QB], rsn[QB], fct[QB];
  __shared__ int flags[2];

  const int tid = threadIdx.x;
  const int lane = tid & 63, wv = tid >> 6;
  const int fr = lane & 15, fq = lane >> 4;
  const int z = blockIdx.x & 7;            // XCD-aligned: same z -> same XCD
  const int q0 = (blockIdx.x >> 3) * QB;
  const long NEL = (long)LL * CB;
  const u16* qz = qT + z * NEL;
  const u16* kz = kT + z * NEL;
  const u16* vz = vN + z * NEL;
  const float cl = 0.04419417382f * 1.44269504f;   // C^-0.5 * log2(e)

  // ---- staging (8 gload_lds / thread each; rule #21 pre-swizzled source) ----
  auto stageK = [&](int j0) {
#pragma unroll
    for (int p = 0; p < 8; ++p) {
      int t = p * 512 + tid;               // 16B-chunk id (4096 per tile)
      int key = t >> 6, ch = t & 63;
      gload16(kz + (long)(j0 + key) * CB + ((ch ^ (key & 7)) << 3), &lK[t * 8]);
    }
  };
  auto stageV = [&](int j0) {
#pragma unroll
    for (int p = 0; p < 8; ++p) {
      int t = p * 512 + tid;
      int d = t >> 3, ch = t & 7;
      gload16(vz + (long)d * LL + j0 + ((ch ^ (d & 7)) << 3), &lV[t * 8]);
    }
  };

  // prologue: stage K(0), V(0); Q frags; init stats
  stageK(0);
  stageV(0);
  short8 qf[16];
#pragma unroll
  for (int ks = 0; ks < 16; ++ks)
    qf[ks] = *(const short8*)(qz + (long)(q0 + wv * 16 + fr) * CB + ks * 32 + fq * 8);
  if (tid < QB) { mst[tid] = -3e38f; lst[tid] = 0.f; }
  if (tid == 0) { flags[0] = 0; flags[1] = 0; }

  f32x4 acc[8][4];
#pragma unroll
  for (int m = 0; m < 8; ++m)
#pragma unroll
    for (int n = 0; n < 4; ++n) acc[m][n] = (f32x4)(0.f);

  bar_vm0_lgkm();

  for (int i = 0; i < 64; ++i) {
    // ---- phase A: S = Q * K^T  (reads lK + qf regs; V(i) may be in flight) --
    f32x4 sa[4];
#pragma unroll
    for (int n = 0; n < 4; ++n) sa[n] = (f32x4)(0.f);
#pragma unroll
    for (int ks = 0; ks < 16; ++ks) {
#pragma unroll
      for (int n = 0; n < 4; ++n) {
        const int key = n * 16 + fr;
        const short8 kf = *(const short8*)&lK[key * 512 + ((ks * 32 + fq * 8) ^ ((key & 7) << 3))];
        sa[n] = __builtin_amdgcn_mfma_f32_16x16x32_bf16(qf[ks], kf, sa[n], 0, 0, 0);
      }
    }
    bar_lgkm();                                   // K(i) consumed by all waves

    // ---- phase B: issue K(i+1) (wraps harmlessly on last iter) -------------
    stageK(((i + 1) & 63) * KB);

    // ---- phase C: row-max candidate ----------------------------------------
    float u[4][4];
#pragma unroll
    for (int n = 0; n < 4; ++n)
#pragma unroll
      for (int r = 0; r < 4; ++r) u[n][r] = sa[n][r] * cl;
    float rm[4];
#pragma unroll
    for (int r = 0; r < 4; ++r)
      rm[r] = fmaxf(fmaxf(u[0][r], u[1][r]), fmaxf(u[2][r], u[3][r]));
#pragma unroll
    for (int r = 0; r < 4; ++r) {
#pragma unroll
      for (int msk = 1; msk <= 8; msk <<= 1) rm[r] = fmaxf(rm[r], __shfl_xor(rm[r], msk));
    }
    if (fr == 0) {
#pragma unroll
      for (int r = 0; r < 4; ++r) rsn[wv * 16 + fq * 4 + r] = rm[r];
    }
    bar_lgkm();

    // ---- phase D: stats update (defer-max) ---------------------------------
    if (tid < QB) {
      float mo = mst[tid], rn = rsn[tid];
      bool need = rn > mo + 11.5f;                // THR = 8 nats in log2 units
      float mn = need ? rn : mo;
      mxn[tid] = mn;
      fct[tid] = need ? exp2f(mo - mn) : 1.0f;
      mst[tid] = mn;
      if (need) flags[i & 1] = 1;
    }
    if (tid == 256) flags[(i + 1) & 1] = 0;
    bar_lgkm();

    // ---- phase E: exp, P write, rescale ------------------------------------
    float mr[4];
#pragma unroll
    for (int r = 0; r < 4; ++r) mr[r] = mxn[wv * 16 + fq * 4 + r];
    float rs[4] = {0.f, 0.f, 0.f, 0.f};
    u16 pb[4][4];
#pragma unroll
    for (int n = 0; n < 4; ++n)
#pragma unroll
      for (int r = 0; r < 4; ++r) {
        float p = exp2f(u[n][r] - mr[r]);
        rs[r] += p;
        pb[n][r] = f2bf(p);
      }
#pragma unroll
    for (int r = 0; r < 4; ++r) {
#pragma unroll
      for (int msk = 1; msk <= 8; msk <<= 1) rs[r] += __shfl_xor(rs[r], msk);
    }
    if (fr == 0) {
#pragma unroll
      for (int r = 0; r < 4; ++r) rsn[wv * 16 + fq * 4 + r] = rs[r];
    }
#pragma unroll
    for (int n = 0; n < 4; ++n)
#pragma unroll
      for (int r = 0; r < 4; ++r) {
        const int row = wv * 16 + fq * 4 + r;
        lP[row * 64 + ((n * 16 + fr) ^ ((row & 7) << 3))] = pb[n][r];
      }
    if (flags[i & 1]) {
#pragma unroll
      for (int m = 0; m < 8; ++m)
#pragma unroll
        for (int r = 0; r < 4; ++r) {
          const float f = fct[m * 16 + fq * 4 + r];
#pragma unroll
          for (int n = 0; n < 4; ++n) acc[m][n][r] *= f;
        }
    }
    bar_vm8_lgkm();                     // P visible; V(i) drained (K(i+1) flies)

    // ---- phase F: PV accumulate + l-update ---------------------------------
#pragma unroll
    for (int ks2 = 0; ks2 < 2; ++ks2) {
      short8 bfv[4];
#pragma unroll
      for (int n = 0; n < 4; ++n) {
        const int d = wv * 64 + n * 16 + fr;
        bfv[n] = *(const short8*)&lV[d * 64 + ((ks2 * 32 + fq * 8) ^ ((d & 7) << 3))];
      }
#pragma unroll
      for (int m = 0; m < 8; ++m) {
        const int row = m * 16 + fr;
        const short8 pa = *(const short8*)&lP[row * 64 + ((ks2 * 32 + fq * 8) ^ ((row & 7) << 3))];
#pragma unroll
        for (int n = 0; n < 4; ++n)
          acc[m][n] = __builtin_amdgcn_mfma_f32_16x16x32_bf16(pa, bfv[n], acc[m][n], 0, 0, 0);
      }
    }
    if (tid < QB) lst[tid] = lst[tid] * fct[tid] + rsn[tid];
    bar_lgkm();                                   // V(i), P consumed

    // ---- phase G: issue V(i+1); wait K(i+1) --------------------------------
    stageV(((i + 1) & 63) * KB);
    bar_vm8_lgkm();                               // K(i+1) ready; V(i+1) flies
  }

  bar_vm0_lgkm();                                 // drain wrap-around stages

  // ---- epilogue: normalize, repack via LDS, coalesced store ---------------
  u16* ob = smem;                                 // [128][512] swz: e8 ^= (row&7)
#pragma unroll
  for (int m = 0; m < 8; ++m)
#pragma unroll
    for (int r = 0; r < 4; ++r) {
      const int row = m * 16 + fq * 4 + r;
      const float il = 1.0f / lst[row];
#pragma unroll
      for (int n = 0; n < 4; ++n) {
        const int d = wv * 64 + n * 16 + fr;
        ob[row * 512 + (d ^ ((row & 7) << 3))] = f2bf(acc[m][n][r] * il);
      }
    }
  bar_lgkm();
#pragma unroll
  for (int p = 0; p < 16; ++p) {
    int t = p * 512 + tid;                        // 8-elem chunk id
    int row = t >> 6, ch = t & 63;
    short8 val = *(const short8*)&ob[row * 512 + ((ch * 8) ^ ((row & 7) << 3))];
    *(short8*)(aT + z * NEL + (long)(q0 + row) * CB + ch * 8) = val;
  }
}

// ---------------------------------------------------------------------------
extern "C" void kernel_launch(void* const* d_in, const int* in_sizes, int n_in,
                              void* d_out, int out_size, void* d_ws, size_t ws_size,
                              hipStream_t stream) {
  const float* x   = (const float*)d_in[0];
  const float* gnw = (const float*)d_in[1];
  const float* gnb = (const float*)d_in[2];
  const float* wq  = (const float*)d_in[3];
  const float* bq  = (const float*)d_in[4];
  const float* wk  = (const float*)d_in[5];
  const float* bk  = (const float*)d_in[6];
  const float* wv  = (const float*)d_in[7];
  const float* bv  = (const float*)d_in[8];
  const float* wo  = (const float*)d_in[9];
  const float* bo  = (const float*)d_in[10];
  float* out = (float*)d_out;

  char* ws = (char*)d_ws;
  const long NEL = (long)LL * CB;
  float* stats = (float*)ws;                               // 8 KB
  float* bqkv  = (float*)(ws + 8192);                      // 6 KB
  u16* wqkv = (u16*)(ws + 16384);                          // 1.5 MB
  u16* wob  = (u16*)(ws + 16384 + 1572864);                // 0.5 MB
  u16* hT   = (u16*)(ws + (4l << 20));                     // 32 MB  [B][L][C]
  u16* qT   = hT + 8 * NEL;                                // 32 MB  [B][L][C]
  u16* kT   = qT + 8 * NEL;                                // 32 MB  [B][L][C]
  u16* vN   = kT + 8 * NEL;                                // 32 MB  [B][C][L]
  u16* aT   = hT;                                          // alias: hT dead after QKV

  conv_w<<<1025, 256, 0, stream>>>(wq, wk, wv, wo, bq, bk, bv, wqkv, wob, bqkv);
  gn_stats<<<256, 256, 0, stream>>>(x, stats);
  gn_apply<<<dim3(64, 8, 8), 256, 0, stream>>>(x, gnw, gnb, stats, hT);

  // fused QKV: A=wqkv [1536][512], Bt=hT[b] [4096][512]
  gemm_bt<128, 128, 0><<<dim3(32, 12, 8), 256, 0, stream>>>(
      wqkv, 512, 0, hT, 512, NEL, 512, bqkv, qT, kT, vN, nullptr, nullptr, 0, 0);

  // fused flash attention: 256 blocks (32 q-tiles x 8 z), 8 waves each
  attn_flash<<<256, 512, 0, stream>>>(qT, kT, vN, aT);

  // out = x + wo * attnT^T + bo
  gemm_bt<128, 128, 3><<<dim3(32, 4, 8), 256, 0, stream>>>(
      wob, 512, 0, aT, 512, NEL, 512, bo,
      nullptr, nullptr, nullptr, out, x, NEL, LL);

  (void)in_sizes; (void)n_in; (void)out_size; (void)ws_size;
}

// Round 4
// 692.940 us; speedup vs baseline: 1.8160x; 1.8160x over previous
//
#include <hip/hip_runtime.h>
#include <hip/hip_bf16.h>
#include <math.h>

#define DI __device__ __forceinline__

typedef unsigned short u16;
typedef unsigned int   u32;
typedef unsigned long long u64;
typedef __attribute__((ext_vector_type(8))) short short8;   // 8 bf16 (4 VGPRs) MFMA A/B frag
typedef __attribute__((ext_vector_type(4))) float f32x4;    // MFMA C/D frag

constexpr int CB = 512;    // channels
constexpr int LL = 4096;   // length
constexpr int NG = 32;     // groups

DI float bf2f(u16 u) { u32 v = ((u32)u) << 16; float f; __builtin_memcpy(&f, &v, 4); return f; }
DI u16 f2bf(float f) {
  u32 u; __builtin_memcpy(&u, &f, 4);
  u += 0x7fffu + ((u >> 16) & 1u);   // RNE
  return (u16)(u >> 16);
}

DI void gload16(const void* g, void* l) {
  __builtin_amdgcn_global_load_lds((const __attribute__((address_space(1))) u32*)g,
                                   (__attribute__((address_space(3))) u32*)l, 16, 0, 0);
}

// ---------------------------------------------------------------------------
// K0: weights -> bf16 (wqkv fused [1536][512], wo [512][512]); fused bias.
// ---------------------------------------------------------------------------
__global__ __launch_bounds__(256) void conv_w(
    const float* __restrict__ wq, const float* __restrict__ wk,
    const float* __restrict__ wv, const float* __restrict__ wo,
    const float* __restrict__ bq, const float* __restrict__ bk,
    const float* __restrict__ bv,
    u16* __restrict__ wqkv, u16* __restrict__ wob, float* __restrict__ bqkv) {
  if (blockIdx.x < 1024) {
    int i = blockIdx.x * 256 + threadIdx.x;
    wqkv[i]          = f2bf(wq[i]);
    wqkv[262144 + i] = f2bf(wk[i]);
    wqkv[524288 + i] = f2bf(wv[i]);
    wob[i]           = f2bf(wo[i]);
  } else {
    for (int j = 0; j < 6; ++j) {
      int idx = j * 256 + threadIdx.x;
      float b = (idx < 512) ? bq[idx] : (idx < 1024) ? bk[idx - 512] : bv[idx - 1024];
      bqkv[idx] = b;
    }
  }
}

// ---------------------------------------------------------------------------
// K1: GroupNorm stats. One block per (b,g).
// ---------------------------------------------------------------------------
__global__ __launch_bounds__(256) void gn_stats(const float* __restrict__ x,
                                                float* __restrict__ stats) {
  const float4* base = (const float4*)(x + (long)blockIdx.x * (16 * LL));
  float s = 0.f, ss = 0.f;
  for (int i = threadIdx.x; i < 16 * LL / 4; i += 256) {
    float4 v = base[i];
    s  += v.x + v.y + v.z + v.w;
    ss += v.x * v.x + v.y * v.y + v.z * v.z + v.w * v.w;
  }
#pragma unroll
  for (int o = 32; o; o >>= 1) { s += __shfl_xor(s, o); ss += __shfl_xor(ss, o); }
  __shared__ float red[8];
  int wv = threadIdx.x >> 6, ln = threadIdx.x & 63;
  if (ln == 0) { red[wv * 2] = s; red[wv * 2 + 1] = ss; }
  __syncthreads();
  if (threadIdx.x == 0) {
    float S = red[0] + red[2] + red[4] + red[6];
    float SS = red[1] + red[3] + red[5] + red[7];
    float mu = S * (1.f / 65536.f);
    float var = SS * (1.f / 65536.f) - mu * mu;
    stats[blockIdx.x * 2]     = mu;
    stats[blockIdx.x * 2 + 1] = rsqrtf(var + 1e-6f);
  }
}

// ---------------------------------------------------------------------------
// K2: GroupNorm apply + transpose: hT[b][l][c] = bf16(gn(x[b][c][l]))
// ---------------------------------------------------------------------------
__global__ __launch_bounds__(256) void gn_apply(
    const float* __restrict__ x, const float* __restrict__ gw,
    const float* __restrict__ gb, const float* __restrict__ stats,
    u16* __restrict__ hT) {
  __shared__ u16 t[64][66];
  const int b = blockIdx.z, c0 = blockIdx.y * 64, l0 = blockIdx.x * 64;
  const int ln = threadIdx.x & 63, sub = threadIdx.x >> 6;
  for (int cr = sub; cr < 64; cr += 4) {
    int c = c0 + cr;
    float v  = x[(long)b * CB * LL + (long)c * LL + l0 + ln];
    float mu = stats[(b * NG + (c >> 4)) * 2];
    float rs = stats[(b * NG + (c >> 4)) * 2 + 1];
    t[cr][ln] = f2bf((v - mu) * rs * gw[c] + gb[c]);
  }
  __syncthreads();
  for (int lr = sub; lr < 64; lr += 4)
    hT[(long)b * LL * CB + (long)(l0 + lr) * CB + c0 + ln] = t[ln][lr];
}

// ---------------------------------------------------------------------------
// Shared GEMM skeleton: D[M][N] = A[M][K] * Bt[N][K]^T  (both k-contiguous)
// BK=64, 4 waves (2x2), 16x16x32 bf16 MFMA, LDS XOR-swizzled staging
// (linear global_load_lds dest + pre-swizzled global source — rule #21).
// bf16 epilogues repack the output tile through LDS -> 16B/lane stores.
// EPI: 0=QKV (q/k stored transposed [l][c], v natural [c][l]; +bias)
//      1=S (bf16, *scale, + z-stride osb)  2=PV (bf16, + z-stride osb)
//      3=out (fp32 +bias +residual)
//      4=PV split-K: blockIdx.z = (g<<1)|chunk; K=chunk length; partial
//        bf16 tile -> (chunk? o1 : o0) + g*LL*CB  (dead qT/kT planes)
// SWZ: bijective XCD-chunked blockIdx swizzle (requires nwg%8==0).
// ---------------------------------------------------------------------------
template <int BM, int BN, int EPI, bool SWZ>
__global__ __launch_bounds__(256) void gemm_bt(
    const u16* __restrict__ A, int lda, long asb,
    const u16* __restrict__ Bt, int ldb, long bsb,
    int K, const float* __restrict__ bias, float scale,
    u16* __restrict__ o0, u16* __restrict__ o1, u16* __restrict__ o2,
    float* __restrict__ of, const float* __restrict__ xres, long osb, int ldo) {
  constexpr int FM = BM / 32, FN = BN / 32;
  __shared__ u16 smem[(BM + BN) * 64];
  u16* lA = smem;
  u16* lB = smem + BM * 64;

  int bx = blockIdx.x, by = blockIdx.y;
  if constexpr (SWZ) {
    const int nwg = gridDim.x * gridDim.y;
    const int id = by * gridDim.x + bx;
    const int id2 = (id & 7) * (nwg >> 3) + (id >> 3);
    bx = id2 % gridDim.x;
    by = id2 / gridDim.x;
  }

  const int tid = threadIdx.x;
  const int lane = tid & 63;
  const int wv = tid >> 6;
  const int wr = wv >> 1, wc = wv & 1;
  const int fr = lane & 15, fq = lane >> 4;
  const int bz = blockIdx.z;
  const int bzb  = (EPI == 4) ? (bz >> 1) : bz;     // batch index
  const int kbeg = (EPI == 4) ? (bz & 1) * K : 0;   // split-K chunk start

  const u16* Ab = A + (long)bzb * asb + (long)(by * BM) * lda;
  const u16* Bb = Bt + (long)bzb * bsb + (long)(bx * BN) * ldb;

  f32x4 acc[FM][FN];
#pragma unroll
  for (int m = 0; m < FM; ++m)
#pragma unroll
    for (int n = 0; n < FN; ++n) acc[m][n] = (f32x4)(0.f);

  for (int k0 = kbeg; k0 < kbeg + K; k0 += 64) {
#pragma unroll
    for (int p = 0; p < BM / 32; ++p) {
      int t = p * 256 + tid;
      int row = t >> 3;
      int cbl = ((t & 7) << 4) ^ ((row & 7) << 4);     // inverse-swizzled source col (bytes)
      gload16(Ab + (long)row * lda + k0 + (cbl >> 1), &lA[t * 8]);
    }
#pragma unroll
    for (int p = 0; p < BN / 32; ++p) {
      int t = p * 256 + tid;
      int row = t >> 3;
      int cbl = ((t & 7) << 4) ^ ((row & 7) << 4);
      gload16(Bb + (long)row * ldb + k0 + (cbl >> 1), &lB[t * 8]);
    }
    __syncthreads();
#pragma unroll
    for (int ks = 0; ks < 2; ++ks) {
      short8 af[FM], bfr[FN];
#pragma unroll
      for (int m = 0; m < FM; ++m) {
        int row = wr * (BM / 2) + m * 16 + fr;
        int cb = (ks * 64 + fq * 16) ^ ((row & 7) << 4);
        af[m] = *(const short8*)((const char*)lA + row * 128 + cb);
      }
#pragma unroll
      for (int n = 0; n < FN; ++n) {
        int row = wc * (BN / 2) + n * 16 + fr;
        int cb = (ks * 64 + fq * 16) ^ ((row & 7) << 4);
        bfr[n] = *(const short8*)((const char*)lB + row * 128 + cb);
      }
#pragma unroll
      for (int m = 0; m < FM; ++m)
#pragma unroll
        for (int n = 0; n < FN; ++n)
          acc[m][n] = __builtin_amdgcn_mfma_f32_16x16x32_bf16(af[m], bfr[n], acc[m][n], 0, 0, 0);
    }
    __syncthreads();
  }

  const int ml0 = wr * (BM / 2);
  const int nl0 = wc * (BN / 2);

  if constexpr (EPI == 3) {
    const int mg0 = by * BM + ml0;
    const int ng0 = bx * BN + nl0;
#pragma unroll
    for (int m = 0; m < FM; ++m)
#pragma unroll
      for (int n = 0; n < FN; ++n) {
        const int ng = ng0 + n * 16 + fr;
#pragma unroll
        for (int r = 0; r < 4; ++r) {
          const int mg = mg0 + m * 16 + fq * 4 + r;
          const long off = (long)bz * osb + (long)mg * ldo + ng;
          of[off] = acc[m][n][r] + bias[mg] + xres[off];
        }
      }
  } else if constexpr (EPI == 0) {
    const int mat = (by * BM) >> 9;
    if (mat < 2) {
      // q/k: transposed tile in LDS: row = l (nl), col = c (ml), width BM
#pragma unroll
      for (int m = 0; m < FM; ++m)
#pragma unroll
        for (int n = 0; n < FN; ++n) {
          const int nl = nl0 + n * 16 + fr;
#pragma unroll
          for (int r = 0; r < 4; ++r) {
            const int ml = ml0 + m * 16 + fq * 4 + r;
            smem[nl * BM + (ml ^ ((nl & 7) << 3))] =
                f2bf(acc[m][n][r] + bias[by * BM + ml]);
          }
        }
      __syncthreads();
      u16* dst0 = (mat == 0 ? o0 : o1) + (long)bz * ((long)LL * CB) +
                  (long)(bx * BN) * CB + ((by * BM) & 511);
      for (int i = tid * 8; i < BM * BN; i += 2048) {
        const int rr = i / BM, cc = i % BM;
        short8 val = *(const short8*)&smem[rr * BM + (cc ^ ((rr & 7) << 3))];
        *(short8*)(dst0 + (long)rr * CB + cc) = val;
      }
    } else {
      // v: natural tile: row = c (ml), col = l (nl), width BN
#pragma unroll
      for (int m = 0; m < FM; ++m)
#pragma unroll
        for (int n = 0; n < FN; ++n) {
          const int nl = nl0 + n * 16 + fr;
#pragma unroll
          for (int r = 0; r < 4; ++r) {
            const int ml = ml0 + m * 16 + fq * 4 + r;
            smem[ml * BN + (nl ^ ((ml & 7) << 3))] =
                f2bf(acc[m][n][r] + bias[by * BM + ml]);
          }
        }
      __syncthreads();
      u16* dst0 = o2 + (long)bz * ((long)CB * LL) +
                  (long)((by * BM) & 511) * LL + bx * BN;
      for (int i = tid * 8; i < BM * BN; i += 2048) {
        const int rr = i / BN, cc = i % BN;
        short8 val = *(const short8*)&smem[rr * BN + (cc ^ ((rr & 7) << 3))];
        *(short8*)(dst0 + (long)rr * LL + cc) = val;
      }
    }
  } else {
    // EPI 1/2/4: row-major [m][n] bf16 tile (scaled for EPI 1)
#pragma unroll
    for (int m = 0; m < FM; ++m)
#pragma unroll
      for (int n = 0; n < FN; ++n) {
        const int nl = nl0 + n * 16 + fr;
#pragma unroll
        for (int r = 0; r < 4; ++r) {
          const int ml = ml0 + m * 16 + fq * 4 + r;
          smem[ml * BN + (nl ^ ((ml & 7) << 3))] = f2bf(acc[m][n][r] * scale);
        }
      }
    __syncthreads();
    u16* dst0;
    if constexpr (EPI == 4)
      dst0 = ((bz & 1) ? o1 : o0) + (long)(bz >> 1) * ((long)LL * CB) +
             (long)(by * BM) * ldo + bx * BN;
    else
      dst0 = o0 + (long)bz * osb + (long)(by * BM) * ldo + bx * BN;
    for (int i = tid * 8; i < BM * BN; i += 2048) {
      const int rr = i / BN, cc = i % BN;
      short8 val = *(const short8*)&smem[rr * BN + (cc ^ ((rr & 7) << 3))];
      *(short8*)(dst0 + (long)rr * ldo + cc) = val;
    }
  }
}

// ---------------------------------------------------------------------------
// K4: row softmax in-place on bf16 S [G][4096][4096]; block = one row.
// ---------------------------------------------------------------------------
__global__ __launch_bounds__(256) void softmax_row(u16* __restrict__ S) {
  u16* row = S + ((long)blockIdx.y * LL + blockIdx.x) * LL;
  const int tid = threadIdx.x;
  const int wv = tid >> 6, ln = tid & 63;
  short8 a = ((const short8*)row)[tid * 2];
  short8 b = ((const short8*)row)[tid * 2 + 1];
  float v[16];
#pragma unroll
  for (int j = 0; j < 8; ++j) { v[j] = bf2f((u16)a[j]); v[8 + j] = bf2f((u16)b[j]); }
  float mx = -1e30f;
#pragma unroll
  for (int j = 0; j < 16; ++j) mx = fmaxf(mx, v[j]);
#pragma unroll
  for (int o = 32; o; o >>= 1) mx = fmaxf(mx, __shfl_xor(mx, o));
  __shared__ float red[4];
  if (ln == 0) red[wv] = mx;
  __syncthreads();
  mx = fmaxf(fmaxf(red[0], red[1]), fmaxf(red[2], red[3]));
  __syncthreads();
  float sum = 0.f;
#pragma unroll
  for (int j = 0; j < 16; ++j) { v[j] = __expf(v[j] - mx); sum += v[j]; }
#pragma unroll
  for (int o = 32; o; o >>= 1) sum += __shfl_xor(sum, o);
  if (ln == 0) red[wv] = sum;
  __syncthreads();
  sum = red[0] + red[1] + red[2] + red[3];
  const float r = 1.f / sum;
  short8 o1, o2;
#pragma unroll
  for (int j = 0; j < 8; ++j) { o1[j] = (short)f2bf(v[j] * r); o2[j] = (short)f2bf(v[8 + j] * r); }
  ((short8*)row)[tid * 2] = o1;
  ((short8*)row)[tid * 2 + 1] = o2;
}

// ---------------------------------------------------------------------------
// K5: sum two bf16 partial planes -> bf16 out plane.  grid (512, G).
// ---------------------------------------------------------------------------
__global__ __launch_bounds__(256) void reduce_pp(
    const u16* __restrict__ p0, const u16* __restrict__ p1, u16* __restrict__ o) {
  const long base = (long)blockIdx.y * ((long)LL * CB) +
                    (long)(blockIdx.x * 256 + threadIdx.x) * 16;
#pragma unroll
  for (int h = 0; h < 2; ++h) {
    short8 a = *(const short8*)(p0 + base + h * 8);
    short8 b = *(const short8*)(p1 + base + h * 8);
    short8 r;
#pragma unroll
    for (int j = 0; j < 8; ++j)
      r[j] = (short)f2bf(bf2f((u16)a[j]) + bf2f((u16)b[j]));
    *(short8*)(o + base + h * 8) = r;
  }
}

// ---------------------------------------------------------------------------
extern "C" void kernel_launch(void* const* d_in, const int* in_sizes, int n_in,
                              void* d_out, int out_size, void* d_ws, size_t ws_size,
                              hipStream_t stream) {
  const float* x   = (const float*)d_in[0];
  const float* gnw = (const float*)d_in[1];
  const float* gnb = (const float*)d_in[2];
  const float* wq  = (const float*)d_in[3];
  const float* bq  = (const float*)d_in[4];
  const float* wk  = (const float*)d_in[5];
  const float* bk  = (const float*)d_in[6];
  const float* wv  = (const float*)d_in[7];
  const float* bv  = (const float*)d_in[8];
  const float* wo  = (const float*)d_in[9];
  const float* bo  = (const float*)d_in[10];
  float* out = (float*)d_out;

  char* ws = (char*)d_ws;
  const long NEL = (long)LL * CB;          // 2M elems = 4 MB bf16 per batch-plane
  const long SEL = (long)LL * LL;          // 16M elems = 32 MB bf16 per batch S
  float* stats = (float*)ws;                               // 8 KB
  float* bqkv  = (float*)(ws + 8192);                      // 6 KB
  u16* wqkv = (u16*)(ws + 16384);                          // 1.5 MB
  u16* wob  = (u16*)(ws + 16384 + 1572864);                // 0.5 MB
  u16* hT   = (u16*)(ws + (4l << 20));                     // 32 MB  [B][L][C]
  u16* qT   = hT + 8 * NEL;                                // 32 MB  [B][L][C]
  u16* kT   = qT + 8 * NEL;                                // 32 MB  [B][L][C]
  u16* vN   = kT + 8 * NEL;                                // 32 MB  [B][C][L]
  const size_t base = (4ul << 20) + 4ul * 8 * NEL * 2;     // 132 MB

  // G = attention batches per round (S buffer = G*32 MB beyond base).
  int G;
  u16 *Sbuf, *aT;
  if (ws_size >= base + 2ul * SEL * 2) G = 2;
  else                                 G = 1;
  if (G > 1) { Sbuf = (u16*)(ws + base); aT = hT; }        // hT dead after QKV
  else       { Sbuf = hT; aT = qT; }                       // legacy aliasing

  conv_w<<<1025, 256, 0, stream>>>(wq, wk, wv, wo, bq, bk, bv, wqkv, wob, bqkv);
  gn_stats<<<256, 256, 0, stream>>>(x, stats);
  gn_apply<<<dim3(64, 8, 8), 256, 0, stream>>>(x, gnw, gnb, stats, hT);

  // fused QKV: A=wqkv [1536][512], Bt=hT[b] [4096][512]
  gemm_bt<128, 128, 0, false><<<dim3(32, 12, 8), 256, 0, stream>>>(
      wqkv, 512, 0, hT, 512, NEL, 512, bqkv, 1.f, qT, kT, vN, nullptr, nullptr, 0, 0);

  const float scal = 1.0f / sqrtf(512.0f);
  for (int g0 = 0; g0 < 8; g0 += G) {
    // S[z] = scale * qT[g0+z] * kT[g0+z]^T : M=N=4096, K=512
    gemm_bt<128, 128, 1, false><<<dim3(32, 32, G), 256, 0, stream>>>(
        qT + (long)g0 * NEL, 512, NEL, kT + (long)g0 * NEL, 512, NEL, 512,
        nullptr, scal, Sbuf, nullptr, nullptr, nullptr, nullptr, SEL, LL);
    softmax_row<<<dim3(LL, G), 256, 0, stream>>>(Sbuf);
    if (G == 2) {
      // PV split-K: attn[g][i][c] = P[i][:] * vN[g][c][:]^T, K=4096 in 2 chunks.
      // Partials -> dead qT/kT planes of this round (bf16), then reduce -> aT.
      gemm_bt<128, 128, 4, false><<<dim3(4, 32, 4), 256, 0, stream>>>(
          Sbuf, LL, SEL, vN + (long)g0 * NEL, LL, NEL, 2048,
          nullptr, 1.f, qT + (long)g0 * NEL, kT + (long)g0 * NEL, nullptr,
          nullptr, nullptr, 0, CB);
      reduce_pp<<<dim3(512, 2), 256, 0, stream>>>(
          qT + (long)g0 * NEL, kT + (long)g0 * NEL, aT + (long)g0 * NEL);
    } else {
      gemm_bt<128, 64, 2, true><<<dim3(8, 32, 1), 256, 0, stream>>>(
          Sbuf, LL, 0, vN + (long)g0 * NEL, LL, 0, LL,
          nullptr, 1.f, aT + (long)g0 * NEL, nullptr, nullptr, nullptr, nullptr, NEL, CB);
    }
  }

  // out = x + wo * attnT^T + bo : M=512, N=4096, K=512 per batch
  gemm_bt<128, 128, 3, false><<<dim3(32, 4, 8), 256, 0, stream>>>(
      wob, 512, 0, aT, 512, NEL, 512, bo, 1.f,
      nullptr, nullptr, nullptr, out, x, NEL, LL);

  (void)in_sizes; (void)n_in; (void)out_size; (void)ws_size;
}